// Round 4
// baseline (83.919 us; speedup 1.0000x reference)
//
#include <hip/hip_runtime.h>
#include <stdint.h>

#define DATA_BITS 57
#define SHIFT_BITS 6
#define ROWS_PER_BLOCK 256
#define BLOCK 256
#define TILE_FLOATS (ROWS_PER_BLOCK * DATA_BITS)      // 14592
#define WORDS (TILE_FLOATS / 64)                      // 228 u64 words per tile
#define NITER (TILE_FLOATS / BLOCK)                   // 57 loads per thread
#define STILE_VEC (ROWS_PER_BLOCK * SHIFT_BITS / 4)   // 384
#define MASK57 ((1ULL << DATA_BITS) - 1ULL)

typedef float floatx4 __attribute__((ext_vector_type(4)));

__device__ __forceinline__ floatx4 expand(const unsigned long long* masks, int p) {
    int row = p / DATA_BITS;                   // magic-mul const div
    int col = p - row * DATA_BITS;
    unsigned long long m = masks[row] >> col;  // same-address b64 reads broadcast
    if (col > DATA_BITS - 4)
        m |= masks[row + 1] << (DATA_BITS - col);
    uint32_t c = (uint32_t)m;
    floatx4 f;
    f.x = __uint_as_float((0u - (c        & 1u)) & 0x3F800000u);
    f.y = __uint_as_float((0u - ((c >> 1) & 1u)) & 0x3F800000u);
    f.z = __uint_as_float((0u - ((c >> 2) & 1u)) & 0x3F800000u);
    f.w = __uint_as_float((0u - ((c >> 3) & 1u)) & 0x3F800000u);
    return f;
}

__global__ __launch_bounds__(BLOCK, 4) void barrel57_kernel(
    const float* __restrict__ X, const float* __restrict__ S,
    float* __restrict__ outCur, float* __restrict__ outSticky,
    int batch)
{
    __shared__ unsigned long long words[WORDS + 2];          // packed input bitstream
    __shared__ unsigned long long maskOut[ROWS_PER_BLOCK + 2];
    __shared__ float stile[ROWS_PER_BLOCK * SHIFT_BITS];     // 6 KB

    const int t    = threadIdx.x;
    const int wave = t >> 6;
    const int lane = t & 63;
    const long long blockRow0 = (long long)blockIdx.x * ROWS_PER_BLOCK;
    const long long xBase = blockRow0 * DATA_BITS;
    const long long sBase = blockRow0 * SHIFT_BITS;
    const bool fullBlock = (blockRow0 + ROWS_PER_BLOCK <= (long long)batch);

    // zero the pad entries (never written elsewhere)
    if (t < 2) { words[WORDS + t] = 0ULL; maskOut[ROWS_PER_BLOCK + t] = 0ULL; }

    const float4* Sv = (const float4*)S + (sBase >> 2);

    if (fullBlock) {
        // ---- stage shift tile (coalesced float4) ----
        #pragma unroll
        for (int k = 0; k < 2; ++k) {
            int i = t + k * BLOCK;
            if (i < STILE_VEC) *(float4*)&stile[i * 4] = Sv[i];
        }
        // ---- phase 1: ballot-pack the tile bitstream; no atomics ----
        const float* Xp = X + xBase;
        #pragma unroll
        for (int k = 0; k < NITER; ++k) {
            float x = Xp[k * BLOCK + t];                     // coalesced dword
            unsigned long long bal = __ballot(x != 0.0f);    // 64 consecutive bits
            if (lane == 0) words[4 * k + wave] = bal;        // one ds_write_b64/wave
        }
    } else {
        const long long totalX = (long long)batch * DATA_BITS;
        const long long totalS = (long long)batch * SHIFT_BITS;
        for (int i = t; i < STILE_VEC; i += BLOCK)
            if (sBase + (long long)i * 4 < totalS) *(float4*)&stile[i * 4] = Sv[i];
        for (int k = 0; k < NITER; ++k) {
            long long g = xBase + (long long)k * BLOCK + t;
            float x = (g < totalX) ? X[g] : 0.0f;
            unsigned long long bal = __ballot(x != 0.0f);
            if (lane == 0) words[4 * k + wave] = bal;        // zero-words for OOB: harmless
        }
    }
    __syncthreads();

    // ---- phase 2: per-row 57-bit mask from adjacent words; shift; sticky ----
    {
        const long long row = blockRow0 + t;
        unsigned long long outm = 0ULL;
        if (row < batch) {
            const int bitpos = t * DATA_BITS;
            const int w0 = bitpos >> 6;
            const int off = bitpos & 63;
            unsigned long long mask = words[w0] >> off;
            if (off) mask |= words[w0 + 1] << (64 - off);
            mask &= MASK57;

            const float* sr = &stile[t * SHIFT_BITS];
            int s = 0;
            #pragma unroll
            for (int l = 0; l < SHIFT_BITS; ++l)
                s |= (int)(sr[l] != 0.0f) << (SHIFT_BITS - 1 - l);

            outm = (mask << s) & MASK57;
            unsigned long long dropped = (s >= DATA_BITS) ? mask : (mask >> (DATA_BITS - s));
            __builtin_nontemporal_store((dropped != 0ULL) ? 1.0f : 0.0f, &outSticky[row]);
        }
        maskOut[t] = outm;
    }
    __syncthreads();

    // ---- phase 3: expand out-masks -> 0/1 floats, nontemporal float4 stores ----
    floatx4* Ov = (floatx4*)outCur + (xBase >> 2);
    if (fullBlock) {
        #pragma unroll
        for (int k = 0; k < NITER / 4; ++k) {                // 14 full passes
            int i = t + k * BLOCK;
            __builtin_nontemporal_store(expand(maskOut, i * 4), &Ov[i]);
        }
        if (t < (TILE_FLOATS / 4 - (NITER / 4) * BLOCK)) {   // 64-thread tail
            int i = t + (NITER / 4) * BLOCK;
            __builtin_nontemporal_store(expand(maskOut, i * 4), &Ov[i]);
        }
    } else {
        const long long totalX = (long long)batch * DATA_BITS;
        for (int i = t; i < TILE_FLOATS / 4; i += BLOCK)
            if (xBase + (long long)i * 4 < totalX)
                __builtin_nontemporal_store(expand(maskOut, i * 4), &Ov[i]);
    }
}

extern "C" void kernel_launch(void* const* d_in, const int* in_sizes, int n_in,
                              void* d_out, int out_size, void* d_ws, size_t ws_size,
                              hipStream_t stream) {
    const float* X = (const float*)d_in[0];
    const float* S = (const float*)d_in[1];
    const int batch = in_sizes[1] / SHIFT_BITS;       // 1,000,000
    float* outCur = (float*)d_out;                    // batch*57 floats
    float* outSticky = outCur + (long long)batch * DATA_BITS;  // batch floats

    const int grid = (batch + ROWS_PER_BLOCK - 1) / ROWS_PER_BLOCK;
    barrel57_kernel<<<grid, BLOCK, 0, stream>>>(X, S, outCur, outSticky, batch);
}

// Round 5
// 73.066 us; speedup vs baseline: 1.1485x; 1.1485x over previous
//
#include <hip/hip_runtime.h>
#include <stdint.h>

#define DATA_BITS 57
#define SHIFT_BITS 6
#define ROWS_PER_BLOCK 256
#define BLOCK 256
#define TILE_FLOATS (ROWS_PER_BLOCK * DATA_BITS)      // 14592
#define WORDS (TILE_FLOATS / 64)                      // 228 u64 words per tile
#define NITER (TILE_FLOATS / BLOCK)                   // 57 loads per thread
#define STILE_VEC (ROWS_PER_BLOCK * SHIFT_BITS / 4)   // 384
#define MASK57 ((1ULL << DATA_BITS) - 1ULL)

typedef float floatx4 __attribute__((ext_vector_type(4)));

__device__ __forceinline__ floatx4 expand(const unsigned long long* masks, int p) {
    int row = p / DATA_BITS;                   // magic-mul const div
    int col = p - row * DATA_BITS;
    unsigned long long m = masks[row] >> col;  // same-address b64 reads broadcast
    if (col > DATA_BITS - 4)
        m |= masks[row + 1] << (DATA_BITS - col);
    uint32_t c = (uint32_t)m;
    floatx4 f;
    f.x = __uint_as_float((0u - (c        & 1u)) & 0x3F800000u);
    f.y = __uint_as_float((0u - ((c >> 1) & 1u)) & 0x3F800000u);
    f.z = __uint_as_float((0u - ((c >> 2) & 1u)) & 0x3F800000u);
    f.w = __uint_as_float((0u - ((c >> 3) & 1u)) & 0x3F800000u);
    return f;
}

__global__ __launch_bounds__(BLOCK, 4) void barrel57_kernel(
    const float* __restrict__ X, const float* __restrict__ S,
    float* __restrict__ outCur, float* __restrict__ outSticky,
    int batch)
{
    __shared__ unsigned long long words[WORDS + 2];          // packed input bitstream
    __shared__ unsigned long long maskOut[ROWS_PER_BLOCK + 2];
    __shared__ float stile[ROWS_PER_BLOCK * SHIFT_BITS];     // 6 KB

    const int t    = threadIdx.x;
    const int wave = t >> 6;
    const int lane = t & 63;
    const long long blockRow0 = (long long)blockIdx.x * ROWS_PER_BLOCK;
    const long long xBase = blockRow0 * DATA_BITS;
    const long long sBase = blockRow0 * SHIFT_BITS;
    const bool fullBlock = (blockRow0 + ROWS_PER_BLOCK <= (long long)batch);

    if (t < 2) { words[WORDS + t] = 0ULL; maskOut[ROWS_PER_BLOCK + t] = 0ULL; }

    const float4* Sv = (const float4*)S + (sBase >> 2);

    if (fullBlock) {
        // ---- stage ALL X loads into registers first: 57 dword loads in flight ----
        const float* Xp = X + xBase;
        float f[NITER];
        #pragma unroll
        for (int k = 0; k < NITER; ++k) f[k] = Xp[k * BLOCK + t];

        // ---- stage shift tile (coalesced float4) ----
        #pragma unroll
        for (int k = 0; k < 2; ++k) {
            int i = t + k * BLOCK;
            if (i < STILE_VEC) *(float4*)&stile[i * 4] = Sv[i];
        }

        // ---- ballot-pack: one 64-bit word per wave-iteration, no atomics ----
        #pragma unroll
        for (int k = 0; k < NITER; ++k) {
            unsigned long long bal = __ballot(f[k] != 0.0f);
            if (lane == 0) words[4 * k + wave] = bal;        // one ds_write_b64/wave
        }
    } else {
        const long long totalX = (long long)batch * DATA_BITS;
        const long long totalS = (long long)batch * SHIFT_BITS;
        for (int i = t; i < STILE_VEC; i += BLOCK)
            if (sBase + (long long)i * 4 < totalS) *(float4*)&stile[i * 4] = Sv[i];
        for (int k = 0; k < NITER; ++k) {
            long long g = xBase + (long long)k * BLOCK + t;
            float x = (g < totalX) ? X[g] : 0.0f;
            unsigned long long bal = __ballot(x != 0.0f);
            if (lane == 0) words[4 * k + wave] = bal;        // zero-words for OOB: harmless
        }
    }
    __syncthreads();

    // ---- phase 2: per-row 57-bit mask from adjacent words; shift; sticky ----
    {
        const long long row = blockRow0 + t;
        unsigned long long outm = 0ULL;
        if (row < batch) {
            const int bitpos = t * DATA_BITS;
            const int w0 = bitpos >> 6;
            const int off = bitpos & 63;
            unsigned long long mask = words[w0] >> off;
            if (off) mask |= words[w0 + 1] << (64 - off);
            mask &= MASK57;

            const float* sr = &stile[t * SHIFT_BITS];
            int s = 0;
            #pragma unroll
            for (int l = 0; l < SHIFT_BITS; ++l)
                s |= (int)(sr[l] != 0.0f) << (SHIFT_BITS - 1 - l);

            outm = (mask << s) & MASK57;
            unsigned long long dropped = (s >= DATA_BITS) ? mask : (mask >> (DATA_BITS - s));
            __builtin_nontemporal_store((dropped != 0ULL) ? 1.0f : 0.0f, &outSticky[row]);
        }
        maskOut[t] = outm;
    }
    __syncthreads();

    // ---- phase 3: expand out-masks -> 0/1 floats, nontemporal float4 stores ----
    floatx4* Ov = (floatx4*)outCur + (xBase >> 2);
    if (fullBlock) {
        #pragma unroll
        for (int k = 0; k < NITER / 4; ++k) {                // 14 full passes
            int i = t + k * BLOCK;
            __builtin_nontemporal_store(expand(maskOut, i * 4), &Ov[i]);
        }
        if (t < (TILE_FLOATS / 4 - (NITER / 4) * BLOCK)) {   // 64-thread tail
            int i = t + (NITER / 4) * BLOCK;
            __builtin_nontemporal_store(expand(maskOut, i * 4), &Ov[i]);
        }
    } else {
        const long long totalX = (long long)batch * DATA_BITS;
        for (int i = t; i < TILE_FLOATS / 4; i += BLOCK)
            if (xBase + (long long)i * 4 < totalX)
                __builtin_nontemporal_store(expand(maskOut, i * 4), &Ov[i]);
    }
}

extern "C" void kernel_launch(void* const* d_in, const int* in_sizes, int n_in,
                              void* d_out, int out_size, void* d_ws, size_t ws_size,
                              hipStream_t stream) {
    const float* X = (const float*)d_in[0];
    const float* S = (const float*)d_in[1];
    const int batch = in_sizes[1] / SHIFT_BITS;       // 1,000,000
    float* outCur = (float*)d_out;                    // batch*57 floats
    float* outSticky = outCur + (long long)batch * DATA_BITS;  // batch floats

    const int grid = (batch + ROWS_PER_BLOCK - 1) / ROWS_PER_BLOCK;
    barrel57_kernel<<<grid, BLOCK, 0, stream>>>(X, S, outCur, outSticky, batch);
}

// Round 6
// 72.935 us; speedup vs baseline: 1.1506x; 1.0018x over previous
//
#include <hip/hip_runtime.h>
#include <stdint.h>

#define DATA_BITS 57
#define SHIFT_BITS 6
#define ROWS_PER_BLOCK 256
#define BLOCK 256
#define TILE_FLOATS (ROWS_PER_BLOCK * DATA_BITS)   // 14592 floats = 58368 B
#define TILE_VEC (TILE_FLOATS / 4)                 // 3648 float4
#define NSTAGE (TILE_VEC / 64)                     // 57 global_load_lds_dwordx4 per block
#define MASK57 ((1ULL << DATA_BITS) - 1ULL)

typedef float floatx4 __attribute__((ext_vector_type(4)));

// async global->LDS, 16B per lane; LDS dest = wave-uniform base + lane*16
__device__ __forceinline__ void gload_lds16(const float4* g, float4* l) {
    __builtin_amdgcn_global_load_lds(
        (const __attribute__((address_space(1))) void*)g,
        (__attribute__((address_space(3))) void*)l,
        16, 0, 0);
}

__device__ __forceinline__ floatx4 expand(const unsigned long long* masks, int p) {
    int row = p / DATA_BITS;                   // magic-mul const div
    int col = p - row * DATA_BITS;
    unsigned long long m = masks[row] >> col;  // same-address b64 reads broadcast
    if (col > DATA_BITS - 4)
        m |= masks[row + 1] << (DATA_BITS - col);
    uint32_t c = (uint32_t)m;
    floatx4 f;
    f.x = __uint_as_float((0u - (c        & 1u)) & 0x3F800000u);
    f.y = __uint_as_float((0u - ((c >> 1) & 1u)) & 0x3F800000u);
    f.z = __uint_as_float((0u - ((c >> 2) & 1u)) & 0x3F800000u);
    f.w = __uint_as_float((0u - ((c >> 3) & 1u)) & 0x3F800000u);
    return f;
}

__global__ __launch_bounds__(BLOCK, 2) void barrel57_kernel(
    const float* __restrict__ X, const float* __restrict__ S,
    float* __restrict__ outCur, float* __restrict__ outSticky,
    int batch)
{
    __shared__ float tile[TILE_FLOATS];                      // 58368 B, linear (gload_lds needs it)
    __shared__ unsigned long long maskOut[ROWS_PER_BLOCK + 2];

    const int t    = threadIdx.x;
    const int wave = t >> 6;
    const int lane = t & 63;
    const long long blockRow0 = (long long)blockIdx.x * ROWS_PER_BLOCK;
    const long long xBase = blockRow0 * DATA_BITS;
    const long long row   = blockRow0 + t;
    const bool fullBlock  = (blockRow0 + ROWS_PER_BLOCK <= (long long)batch);

    // ---- per-thread shift bits -> registers; in flight while the tile stages ----
    float sv[SHIFT_BITS];
    if (row < (long long)batch) {
        const float* sp = S + row * SHIFT_BITS;
        #pragma unroll
        for (int l = 0; l < SHIFT_BITS; ++l) sv[l] = sp[l];
    } else {
        #pragma unroll
        for (int l = 0; l < SHIFT_BITS; ++l) sv[l] = 0.0f;
    }

    // ---- async stage X tile -> LDS: 57 fire-and-forget dwordx4 instrs/block ----
    float4* tileV = (float4*)tile;
    if (fullBlock) {
        const float4* Xv = (const float4*)X + (xBase >> 2);
        #pragma unroll
        for (int j = 0; j < (NSTAGE + 3) / 4; ++j) {
            int i = wave + 4 * j;                        // uniform per wave-iteration
            if (i < NSTAGE) gload_lds16(Xv + i * 64 + lane, tileV + i * 64);
        }
    } else {
        const long long totalV = (long long)batch * DATA_BITS / 4;  // exact (57e6 % 4 == 0)
        const long long vBase  = xBase >> 2;
        #pragma unroll
        for (int j = 0; j < (NSTAGE + 3) / 4; ++j) {
            int i = wave + 4 * j;
            if (i < NSTAGE) {
                long long gi = vBase + i * 64 + lane;
                if (gi >= totalV) gi = totalV - 1;       // clamp: dup data lands in unused rows
                gload_lds16((const float4*)X + gi, tileV + i * 64);
            }
        }
    }
    if (t < 2) maskOut[ROWS_PER_BLOCK + t] = 0ULL;
    __syncthreads();   // drains vmcnt(0): staged tile visible

    // ---- pack own row (stride-57 dword reads: 2 lanes/bank = conflict-free) ----
    {
        unsigned long long outm = 0ULL;
        if (row < (long long)batch) {
            const float* r = &tile[t * DATA_BITS];
            uint32_t lo = 0u, hi = 0u;
            #pragma unroll
            for (int k = 0; k < 32; ++k)
                lo |= ((__float_as_uint(r[k]) >> 23) & 1u) << k;
            #pragma unroll
            for (int k = 32; k < DATA_BITS; ++k)
                hi |= ((__float_as_uint(r[k]) >> 23) & 1u) << (k - 32);
            unsigned long long mask = ((unsigned long long)hi << 32) | lo;

            int s = 0;
            #pragma unroll
            for (int l = 0; l < SHIFT_BITS; ++l)
                s |= (int)(sv[l] != 0.0f) << (SHIFT_BITS - 1 - l);

            outm = (mask << s) & MASK57;
            unsigned long long dropped = (s >= DATA_BITS) ? mask : (mask >> (DATA_BITS - s));
            __builtin_nontemporal_store((dropped != 0ULL) ? 1.0f : 0.0f, &outSticky[row]);
        }
        maskOut[t] = outm;
    }
    __syncthreads();

    // ---- expand out-masks -> 0/1 floats, coalesced nontemporal float4 stores ----
    floatx4* Ov = (floatx4*)outCur + (xBase >> 2);
    if (fullBlock) {
        #pragma unroll
        for (int k = 0; k < TILE_VEC / BLOCK; ++k) {         // 14 full passes
            int i = t + k * BLOCK;
            __builtin_nontemporal_store(expand(maskOut, i * 4), &Ov[i]);
        }
        if (t < TILE_VEC - (TILE_VEC / BLOCK) * BLOCK) {     // 64-thread tail
            int i = t + (TILE_VEC / BLOCK) * BLOCK;
            __builtin_nontemporal_store(expand(maskOut, i * 4), &Ov[i]);
        }
    } else {
        const long long totalV = (long long)batch * DATA_BITS / 4;
        const long long vBase  = xBase >> 2;
        for (int i = t; i < TILE_VEC; i += BLOCK)
            if (vBase + i < totalV)
                __builtin_nontemporal_store(expand(maskOut, i * 4), &Ov[i]);
    }
}

extern "C" void kernel_launch(void* const* d_in, const int* in_sizes, int n_in,
                              void* d_out, int out_size, void* d_ws, size_t ws_size,
                              hipStream_t stream) {
    const float* X = (const float*)d_in[0];
    const float* S = (const float*)d_in[1];
    const int batch = in_sizes[1] / SHIFT_BITS;       // 1,000,000
    float* outCur = (float*)d_out;                    // batch*57 floats
    float* outSticky = outCur + (long long)batch * DATA_BITS;  // batch floats

    const int grid = (batch + ROWS_PER_BLOCK - 1) / ROWS_PER_BLOCK;
    barrel57_kernel<<<grid, BLOCK, 0, stream>>>(X, S, outCur, outSticky, batch);
}

// Round 7
// 71.281 us; speedup vs baseline: 1.1773x; 1.0232x over previous
//
#include <hip/hip_runtime.h>
#include <stdint.h>

#define DATA_BITS 57
#define SHIFT_BITS 6
#define BLOCK 256
#define WAVES_PER_BLOCK 4
#define ROWS_PER_WAVE 64
#define WAVE_FLOATS (ROWS_PER_WAVE * DATA_BITS)   // 3648 floats per wave tile
#define NLOAD (WAVE_FLOATS / 64)                  // 57 coalesced loads per wave
#define CHUNK 19                                  // 3 chunks of 19 loads in flight
#define WAVE_VEC (WAVE_FLOATS / 4)                // 912 float4 per wave
#define MASK57 ((1ULL << DATA_BITS) - 1ULL)

typedef float floatx4 __attribute__((ext_vector_type(4)));

__device__ __forceinline__ void lds_fence() {
    asm volatile("s_waitcnt lgkmcnt(0)" ::: "memory");
}

__device__ __forceinline__ floatx4 expand(const unsigned long long* masks, int p) {
    int row = p / DATA_BITS;                   // magic-mul const div
    int col = p - row * DATA_BITS;
    unsigned long long m = masks[row] >> col;  // same-address b64 reads broadcast
    if (col > DATA_BITS - 4)
        m |= masks[row + 1] << (DATA_BITS - col);
    uint32_t c = (uint32_t)m;
    floatx4 f;
    f.x = __uint_as_float((0u - (c        & 1u)) & 0x3F800000u);
    f.y = __uint_as_float((0u - ((c >> 1) & 1u)) & 0x3F800000u);
    f.z = __uint_as_float((0u - ((c >> 2) & 1u)) & 0x3F800000u);
    f.w = __uint_as_float((0u - ((c >> 3) & 1u)) & 0x3F800000u);
    return f;
}

__global__ __launch_bounds__(BLOCK, 8) void barrel57_kernel(
    const float* __restrict__ X, const float* __restrict__ S,
    float* __restrict__ outCur, float* __restrict__ outSticky,
    int batch)
{
    // wave-private scratch; no __syncthreads anywhere
    __shared__ unsigned long long words[WAVES_PER_BLOCK][NLOAD + 2];        // ballot words
    __shared__ unsigned long long maskOut[WAVES_PER_BLOCK][ROWS_PER_WAVE + 2];

    const int t    = threadIdx.x;
    const int wv   = t >> 6;
    const int lane = t & 63;
    const long long W = (long long)blockIdx.x * WAVES_PER_BLOCK + wv;   // global wave id
    const long long nWavesFull = (long long)batch / ROWS_PER_WAVE;      // 15625 (exact)
    const long long row = W * ROWS_PER_WAVE + lane;

    if (W >= nWavesFull) {
        // ---- tail wave (never taken for batch % 64 == 0): scalar, bounds-checked ----
        if (W * ROWS_PER_WAVE >= (long long)batch) return;
        const long long totalF = (long long)batch * DATA_BITS;
        const long long eBase  = W * WAVE_FLOATS;
        if (lane < 2) { words[wv][NLOAD + lane] = 0ULL; maskOut[wv][ROWS_PER_WAVE + lane] = 0ULL; }
        for (int k = 0; k < NLOAD; ++k) {
            long long e = eBase + k * 64 + lane;
            float x = (e < totalF) ? X[e] : 0.0f;
            unsigned long long bal = __ballot(x != 0.0f);
            if (lane == 0) words[wv][k] = bal;
        }
        lds_fence();
        unsigned long long outm = 0ULL;
        if (row < (long long)batch) {
            int bit0 = lane * DATA_BITS, w0 = bit0 >> 6, off = bit0 & 63;
            unsigned long long mask = words[wv][w0] >> off;
            if (off) mask |= words[wv][w0 + 1] << (64 - off);
            mask &= MASK57;
            int s = 0;
            for (int l = 0; l < SHIFT_BITS; ++l)
                s |= (int)(S[row * SHIFT_BITS + l] != 0.0f) << (SHIFT_BITS - 1 - l);
            outm = (mask << s) & MASK57;
            unsigned long long dropped = (s >= DATA_BITS) ? mask : (mask >> (DATA_BITS - s));
            outSticky[row] = (dropped != 0ULL) ? 1.0f : 0.0f;
        }
        maskOut[wv][lane] = outm;
        lds_fence();
        for (int k = 0; k <= NLOAD / 4; ++k) {
            int i = k * 64 + lane;
            if (i < WAVE_VEC) {
                long long e = eBase + i * 4;
                if (e + 3 < totalF) {
                    *((floatx4*)outCur + (eBase >> 2) + i) = expand(maskOut[wv], i * 4);
                } else {
                    floatx4 f = expand(maskOut[wv], i * 4);
                    for (int j = 0; j < 4; ++j) if (e + j < totalF) outCur[e + j] = f[j];
                }
            }
        }
        return;
    }

    // ================= fast path: full wave, no bounds checks =================
    // shift bits for own row -> registers (in flight alongside X loads)
    const float* sp = S + row * SHIFT_BITS;
    float sv[SHIFT_BITS];
    #pragma unroll
    for (int l = 0; l < SHIFT_BITS; ++l) sv[l] = sp[l];

    if (lane < 2) { words[wv][NLOAD + lane] = 0ULL; maskOut[wv][ROWS_PER_WAVE + lane] = 0ULL; }

    // ---- ballot-pack own 3648-float tile: 3 chunks of 19 loads in flight ----
    const float* Xp = X + W * WAVE_FLOATS;
    #pragma unroll
    for (int c = 0; c < 3; ++c) {
        float f[CHUNK];
        #pragma unroll
        for (int j = 0; j < CHUNK; ++j) f[j] = Xp[(c * CHUNK + j) * 64 + lane];
        #pragma unroll
        for (int j = 0; j < CHUNK; ++j) {
            unsigned long long bal = __ballot(f[j] != 0.0f);   // bit l = element 64k+l
            if (lane == 0) words[wv][c * CHUNK + j] = bal;
        }
    }
    lds_fence();   // wave-local: ds_writes visible to own lanes

    // ---- assemble own row's 57-bit mask from 2 adjacent words; shift; sticky ----
    {
        const int bit0 = lane * DATA_BITS;
        const int w0 = bit0 >> 6, off = bit0 & 63;
        unsigned long long mask = words[wv][w0] >> off;
        if (off) mask |= words[wv][w0 + 1] << (64 - off);
        mask &= MASK57;

        int s = 0;
        #pragma unroll
        for (int l = 0; l < SHIFT_BITS; ++l)
            s |= (int)(sv[l] != 0.0f) << (SHIFT_BITS - 1 - l);

        unsigned long long outm = (mask << s) & MASK57;
        unsigned long long dropped = (s >= DATA_BITS) ? mask : (mask >> (DATA_BITS - s));
        __builtin_nontemporal_store((dropped != 0ULL) ? 1.0f : 0.0f, &outSticky[row]);
        maskOut[wv][lane] = outm;
    }
    lds_fence();   // maskOut visible to own lanes

    // ---- expand 912 float4s per wave, coalesced nontemporal stores ----
    floatx4* Ov = (floatx4*)outCur + ((W * WAVE_FLOATS) >> 2);
    #pragma unroll
    for (int k = 0; k < WAVE_VEC / 64; ++k) {                 // 14 full passes
        int i = k * 64 + lane;
        __builtin_nontemporal_store(expand(maskOut[wv], i * 4), &Ov[i]);
    }
    if (lane < WAVE_VEC - (WAVE_VEC / 64) * 64) {             // 16-lane tail
        int i = (WAVE_VEC / 64) * 64 + lane;
        __builtin_nontemporal_store(expand(maskOut[wv], i * 4), &Ov[i]);
    }
}

extern "C" void kernel_launch(void* const* d_in, const int* in_sizes, int n_in,
                              void* d_out, int out_size, void* d_ws, size_t ws_size,
                              hipStream_t stream) {
    const float* X = (const float*)d_in[0];
    const float* S = (const float*)d_in[1];
    const int batch = in_sizes[1] / SHIFT_BITS;       // 1,000,000
    float* outCur = (float*)d_out;                    // batch*57 floats
    float* outSticky = outCur + (long long)batch * DATA_BITS;  // batch floats

    const long long nWaves = ((long long)batch + ROWS_PER_WAVE - 1) / ROWS_PER_WAVE;
    const int grid = (int)((nWaves + WAVES_PER_BLOCK - 1) / WAVES_PER_BLOCK);
    barrel57_kernel<<<grid, BLOCK, 0, stream>>>(X, S, outCur, outSticky, batch);
}